// Round 7
// baseline (181.476 us; speedup 1.0000x reference)
//
#include <hip/hip_runtime.h>

#define D_MODEL 1024
#define N_HEADS 16
#define HEAD_DIM 64
#define SEQ 2048
#define BATCH 2
#define M_TOTAL (BATCH*SEQ)   // 4096

typedef __bf16 bf16;
typedef __bf16 bf16x8 __attribute__((ext_vector_type(8)));
typedef __bf16 bf16x4 __attribute__((ext_vector_type(4)));
typedef float  floatx4 __attribute__((ext_vector_type(4)));

// async global->LDS, 16B per lane. LDS dest is wave-uniform base + lane*16;
// conflicts handled by XOR-swizzle of 16B chunks applied to the GLOBAL source
// address (free).
__device__ __forceinline__ void gl2lds16(const bf16* g, bf16* l) {
    __builtin_amdgcn_global_load_lds(
        (const __attribute__((address_space(1))) unsigned int*)g,
        (__attribute__((address_space(3))) unsigned int*)l, 16, 0, 0);
}

// ---------------------------------------------------------------------------
// one combined fp32->bf16 conversion for q (1M float4), Wq (256K), Wo (256K)
// ---------------------------------------------------------------------------
__global__ void cvt_all(const float* __restrict__ q, const float* __restrict__ Wq,
                        const float* __restrict__ Wo, bf16* __restrict__ qb,
                        bf16* __restrict__ wqb, bf16* __restrict__ wob) {
    int i = blockIdx.x * 256 + threadIdx.x;       // 0 .. 1572863
    const float* src; bf16* dst; int off;
    if (i < 1048576)      { src = q;  dst = qb;  off = i; }
    else if (i < 1310720) { src = Wq; dst = wqb; off = i - 1048576; }
    else                  { src = Wo; dst = wob; off = i - 1310720; }
    float4 v = ((const float4*)src)[off];
    bf16x4 o;
    o[0] = (bf16)v.x; o[1] = (bf16)v.y; o[2] = (bf16)v.z; o[3] = (bf16)v.w;
    ((bf16x4*)dst)[off] = o;
}

// ---------------------------------------------------------------------------
// GEMM C = A * B^T + bias. 128(M)x64(N) tile, BK=32, 256 threads / 4 waves,
// grid 512 = 2 blocks/CU: cross-block overlap hides the per-k-step barrier
// vmcnt(0) drain that a 1-block/CU launch fully exposes (m114 mechanism).
// Double-buffered LDS via global_load_lds(16); tiles unpadded [row][32]
// (64B rows, 4x16B chunks), chunk swizzle c = sp ^ ((row>>1)&3) -> even banks.
// Wave w: wm=(w>>1)*64, wn=(w&1)*32; 4x2 grid of 16x16x32 MFMA.
// Frag layouts (HW-verified): A m=lane&15,k=quad*8+j; C/D col=lane&15,row=quad*4+r.
// MODE 0: fp32 out row-major + bias.
// MODE 1: bf16 out to projbf [B,H,S,Dh] + projT [B,H,Dh,S] via in-LDS transpose
//         (n-extent 64 = exactly one head per block column).
// ---------------------------------------------------------------------------
template<int MODE>
__global__ __launch_bounds__(256)
void gemm_bt_bias_t(const bf16* __restrict__ A, const bf16* __restrict__ B,
                    const float* __restrict__ bias, void* __restrict__ Cout,
                    bf16* __restrict__ Cout2, int M, int N, int K)
{
    __shared__ __align__(16) bf16 smem[12288];   // As[2][4096] | Bs[2][2048] = 24KB
    bf16* As = smem;            // [2][128*32]
    bf16* Bs = smem + 8192;     // [2][64*32]

    const int tid  = threadIdx.x;
    const int lane = tid & 63;
    const int wave = tid >> 6;             // 0..3
    const int quad = lane >> 4;
    const int l16  = lane & 15;
    const int m0   = blockIdx.y * 128;
    const int n0   = blockIdx.x * 64;
    const int wm   = (wave >> 1) * 64;
    const int wn   = (wave & 1) * 32;

    floatx4 acc[4][2];
#pragma unroll
    for (int i = 0; i < 4; i++)
#pragma unroll
        for (int j = 0; j < 2; j++) acc[i][j] = (floatx4){0.f, 0.f, 0.f, 0.f};

    // staging: A 8KB (2 issues/thread), B 4KB (1 issue/thread)
    const int srow = tid >> 2;                        // 0..63
    const int sp   = tid & 3;
    auto issue = [&](int buf, int k0) {
#pragma unroll
        for (int it = 0; it < 2; it++) {
            int row = it * 64 + srow;
            int c   = sp ^ ((row >> 1) & 3);
            gl2lds16(A + (size_t)(m0 + row) * K + k0 + c * 8,
                     &As[buf * 4096 + it * 2048 + tid * 8]);
        }
        {
            int c = sp ^ ((srow >> 1) & 3);
            gl2lds16(B + (size_t)(n0 + srow) * K + k0 + c * 8,
                     &Bs[buf * 2048 + tid * 8]);
        }
    };
    issue(0, 0);
    int buf = 0;
    for (int k0 = 0; k0 < K; k0 += 32, buf ^= 1) {
        __syncthreads();               // drains DMA of tile k0; WAR for buf^1
        if (k0 + 32 < K) issue(buf ^ 1, k0 + 32);
        bf16x8 af[4], bfr[2];
#pragma unroll
        for (int i = 0; i < 4; i++) {
            int row = wm + i * 16 + l16;
            af[i] = *(const bf16x8*)&As[buf * 4096 + row * 32 + ((quad ^ ((row >> 1) & 3)) * 8)];
        }
#pragma unroll
        for (int j = 0; j < 2; j++) {
            int row = wn + j * 16 + l16;
            bfr[j] = *(const bf16x8*)&Bs[buf * 2048 + row * 32 + ((quad ^ ((row >> 1) & 3)) * 8)];
        }
#pragma unroll
        for (int i = 0; i < 4; i++)
#pragma unroll
            for (int j = 0; j < 2; j++)
                acc[i][j] = __builtin_amdgcn_mfma_f32_16x16x32_bf16(
                    af[i], bfr[j], acc[i][j], 0, 0, 0);
    }

    if constexpr (MODE == 0) {
        float* C = (float*)Cout;
#pragma unroll
        for (int j = 0; j < 2; j++) {
            int col  = n0 + wn + j * 16 + l16;
            float bv = bias[col];
#pragma unroll
            for (int i = 0; i < 4; i++) {
                int rbase = m0 + wm + i * 16 + quad * 4;
#pragma unroll
                for (int r = 0; r < 4; r++)
                    C[(size_t)(rbase + r) * N + col] = acc[i][j][r] + bv;
            }
        }
    } else {
        bf16* Cb = (bf16*)Cout;
        const int h  = n0 >> 6;          // tile spans exactly one head
        const int b  = m0 >> 11;         // tile never crosses batch boundary
        bf16x4 tile[4][2];
#pragma unroll
        for (int j = 0; j < 2; j++) {
            int dL   = wn + j * 16 + l16;            // 0..63
            float bv = bias[n0 + dL];
#pragma unroll
            for (int i = 0; i < 4; i++) {
                int sl = wm + i * 16 + quad * 4;     // local s, 0..127
                int s0 = (m0 & 2047) + sl;
#pragma unroll
                for (int r = 0; r < 4; r++) {
                    float v = acc[i][j][r] + bv;
                    tile[i][j][r] = (bf16)v;
                    Cb[(((size_t)(b * N_HEADS + h) * SEQ + (s0 + r)) << 6) + dL] = (bf16)v;
                }
            }
        }
        // in-LDS transpose: T[dL=64][sL=128] (16KB, reuse smem),
        // 16B-chunk swizzle phys = (sl>>3) ^ (dL&15)
        __syncthreads();
#pragma unroll
        for (int j = 0; j < 2; j++) {
            int dL = wn + j * 16 + l16;
#pragma unroll
            for (int i = 0; i < 4; i++) {
                int sl = wm + i * 16 + quad * 4;
                *(bf16x4*)&smem[dL * 128 + (((sl >> 3) ^ (dL & 15)) * 8) + (sl & 7)] =
                    tile[i][j];
            }
        }
        __syncthreads();
        // coalesced projT stores: thread -> (dL = tid>>2, 4 chunks of 16B)
        {
            int dL    = tid >> 2;
            int sbase = m0 & 2047;
            bf16* dstrow = Cout2 + ((size_t)(b * N_HEADS + h) * 64 + dL) * SEQ + sbase;
#pragma unroll
            for (int cc = 0; cc < 4; cc++) {
                int c    = (tid & 3) * 4 + cc;
                int phys = c ^ (dL & 15);
                *(bf16x8*)(dstrow + c * 8) = *(const bf16x8*)&smem[dL * 128 + phys * 8];
            }
        }
    }
}

// ---------------------------------------------------------------------------
// MFMA flash attention. 256-thread / 4-wave blocks (2 waves/SIMD), 32 q/wave,
// 128-q tile, K-tiles of 128 keys, double-buffered K/V DMA prefetch.
// 1-D grid 512 with XCD-pinned mapping: bh=(lin&7)*4+(lin>>7) (FETCH 68->8MB).
// Ks [128 keys][64 d] unpadded, chunk swizzle c^(row&7)  -> even banks.
// Vt [64 d][128 keys] unpadded, chunk swizzle c^(row&15) -> even banks.
// Pt [128 q][40]: per-wave-private rows; written from S^T C-layout as b64.
// S^T: A=K,B=Q -> D[key][q]; PV: A=Vt,B=Pt -> O^T[d][q].
// Softmax: fixed stabilizer, p = exp2(s*log2e/8 - 16*log2e) -- one fma + v_exp
// (scores provably <= ~12, no max pass; validated absmax 0.023).
// ---------------------------------------------------------------------------
__global__ __launch_bounds__(256)
void flash_attn(const bf16* __restrict__ projbf, const bf16* __restrict__ projT,
                bf16* __restrict__ vals)
{
    __shared__ __align__(16) bf16 Ks[2][128 * 64];   // 2 x 16 KB
    __shared__ __align__(16) bf16 Vt[2][64 * 128];   // 2 x 16 KB
    __shared__ __align__(16) bf16 Pt[128 * 40];      // 10 KB

    const int tid  = threadIdx.x;
    const int lane = tid & 63;
    const int wave = tid >> 6;          // 0..3
    const int quad = lane >> 4;
    const int l16  = lane & 15;
    const int lin  = blockIdx.x;
    const int bh   = (lin & 7) * 4 + (lin >> 7);     // XCD-pinned head
    const int q0   = ((lin >> 3) & 15) * 128;
    const bf16* hK  = projbf + (size_t)bh * SEQ * 64;
    const bf16* hVt = projT  + (size_t)bh * 64 * SEQ;
    const int wq0  = wave * 32;

    // persistent Q B-frags: qf[nb][ks], n=q (16 per nb), k=d
    bf16x8 qf[2][2];
#pragma unroll
    for (int nb = 0; nb < 2; nb++)
#pragma unroll
        for (int ks = 0; ks < 2; ks++)
            qf[nb][ks] = *(const bf16x8*)(hK + (size_t)(q0 + wq0 + nb * 16 + l16) * 64
                                          + ks * 32 + quad * 8);

    floatx4 oacc[4][2];                 // [mb=d-block][nb=q-block]
#pragma unroll
    for (int mb = 0; mb < 4; mb++)
#pragma unroll
        for (int nb = 0; nb < 2; nb++) oacc[mb][nb] = (floatx4){0.f, 0.f, 0.f, 0.f};
    float lsum[2] = {0.f, 0.f};

    // DMA one K+V tile pair (32 KB): 4 issues each, 256 threads x 16B
    auto issue = [&](int buf, int k0) {
#pragma unroll
        for (int it = 0; it < 4; it++) {            // K: 32 rows per issue
            int row = it * 32 + (tid >> 3);
            int c   = (tid & 7) ^ (row & 7);
            gl2lds16(hK + (size_t)(k0 + row) * 64 + c * 8,
                     &Ks[buf][it * 2048 + tid * 8]);
        }
#pragma unroll
        for (int it = 0; it < 4; it++) {            // V^T: 16 d-rows per issue
            int row = it * 16 + (tid >> 4);
            int c   = (tid & 15) ^ (row & 15);
            gl2lds16(hVt + (size_t)row * SEQ + k0 + c * 8,
                     &Vt[buf][it * 2048 + tid * 8]);
        }
    };
    issue(0, 0);
    int buf = 0;
    for (int k0 = 0; k0 < SEQ; k0 += 128, buf ^= 1) {
        __syncthreads();                // drains DMA of tile k0 (prefetched); WAR buf^1
        if (k0 + 128 < SEQ) issue(buf ^ 1, k0 + 128);

#pragma unroll
        for (int ck = 0; ck < 4; ck++) {            // 32-key chunks
            // ---- S^T phase ----
#pragma unroll
            for (int kb = 0; kb < 2; kb++) {
                int krow = ck * 32 + kb * 16 + l16;
                bf16x8 kf0 = *(const bf16x8*)&Ks[buf][krow * 64 + ((quad ^ (krow & 7)) * 8)];
                bf16x8 kf1 = *(const bf16x8*)&Ks[buf][krow * 64 + (((4 + quad) ^ (krow & 7)) * 8)];
                floatx4 sacc[2];
#pragma unroll
                for (int nb = 0; nb < 2; nb++) {
                    sacc[nb] = __builtin_amdgcn_mfma_f32_16x16x32_bf16(
                        kf0, qf[nb][0], (floatx4){0.f, 0.f, 0.f, 0.f}, 0, 0, 0);
                    sacc[nb] = __builtin_amdgcn_mfma_f32_16x16x32_bf16(
                        kf1, qf[nb][1], sacc[nb], 0, 0, 0);
                }
#pragma unroll
                for (int nb = 0; nb < 2; nb++) {
                    bf16x4 p4; float ps = 0.f;
#pragma unroll
                    for (int r = 0; r < 4; r++) {
                        // exp(s/8-16) = exp2(s*0.18033688 - 23.083120)
                        float p = exp2f(fmaf(sacc[nb][r], 0.18033688f, -23.083120f));
                        p4[r] = (bf16)p; ps += p;
                    }
                    lsum[nb] += ps;
                    *(bf16x4*)&Pt[(wq0 + nb * 16 + l16) * 40 + kb * 16 + quad * 4] = p4;
                }
            }
            // ---- PV phase over these 32 keys (Pt rows wave-private) ----
            bf16x8 pf[2];
#pragma unroll
            for (int nb = 0; nb < 2; nb++)
                pf[nb] = *(const bf16x8*)&Pt[(wq0 + nb * 16 + l16) * 40 + quad * 8];
#pragma unroll
            for (int mb = 0; mb < 4; mb++) {
                int vrow = mb * 16 + l16;
                bf16x8 vf = *(const bf16x8*)&Vt[buf][vrow * 128
                                                + (((ck * 4 + quad) ^ (vrow & 15)) * 8)];
#pragma unroll
                for (int nb = 0; nb < 2; nb++)
                    oacc[mb][nb] = __builtin_amdgcn_mfma_f32_16x16x32_bf16(
                        vf, pf[nb], oacc[mb][nb], 0, 0, 0);
            }
        }
    }

    // row sums: reduce across quads (each quad summed a disjoint key subset)
#pragma unroll
    for (int nb = 0; nb < 2; nb++) {
        lsum[nb] += __shfl_xor(lsum[nb], 16);
        lsum[nb] += __shfl_xor(lsum[nb], 32);
    }
    const int b = bh >> 4, h = bh & 15;
#pragma unroll
    for (int nb = 0; nb < 2; nb++) {
        float rinv = 1.0f / lsum[nb];
        int q = q0 + wq0 + nb * 16 + l16;
#pragma unroll
        for (int mb = 0; mb < 4; mb++) {
            bf16x4 o4;
#pragma unroll
            for (int r = 0; r < 4; r++) o4[r] = (bf16)(oacc[mb][nb][r] * rinv);
            *(bf16x4*)&vals[((size_t)b * SEQ + q) * D_MODEL + h * 64 + mb * 16 + quad * 4] = o4;
        }
    }
}

// ---------------------------------------------------------------------------
extern "C" void kernel_launch(void* const* d_in, const int* in_sizes, int n_in,
                              void* d_out, int out_size, void* d_ws, size_t ws_size,
                              hipStream_t stream)
{
    const float* q  = (const float*)d_in[0];
    const float* Wq = (const float*)d_in[1];
    const float* bq = (const float*)d_in[2];
    const float* Wo = (const float*)d_in[3];
    const float* bo = (const float*)d_in[4];
    float* out = (float*)d_out;

    char* ws = (char*)d_ws;
    bf16* qbf    = (bf16*)(ws);                        // 8 MB
    bf16* Wqbf   = (bf16*)(ws + (size_t)( 8 << 20));   // 2 MB
    bf16* Wobf   = (bf16*)(ws + (size_t)(10 << 20));   // 2 MB
    bf16* projbf = (bf16*)(ws + (size_t)(12 << 20));   // 8 MB  [B,H,S,Dh]
    bf16* projT  = (bf16*)(ws + (size_t)(20 << 20));   // 8 MB  [B,H,Dh,S]
    bf16* valsb  = (bf16*)(ws + (size_t)(28 << 20));   // 8 MB  [B,S,D]

    cvt_all<<<6144, 256, 0, stream>>>(q, Wq, Wo, qbf, Wqbf, Wobf);

    // proj = q @ Wq^T + bq -> projbf [B,H,S,Dh] + projT [B,H,Dh,S]
    gemm_bt_bias_t<1><<<dim3(16, 32), 256, 0, stream>>>(qbf, Wqbf, bq, (void*)projbf,
                                                        projT, M_TOTAL, D_MODEL, D_MODEL);

    flash_attn<<<512, 256, 0, stream>>>(projbf, projT, valsb);

    gemm_bt_bias_t<0><<<dim3(16, 32), 256, 0, stream>>>(valsb, Wobf, bo, (void*)out,
                                                        nullptr, M_TOTAL, D_MODEL, D_MODEL);
}

// Round 8
// 166.718 us; speedup vs baseline: 1.0885x; 1.0885x over previous
//
#include <hip/hip_runtime.h>

#define D_MODEL 1024
#define N_HEADS 16
#define HEAD_DIM 64
#define SEQ 2048
#define BATCH 2
#define M_TOTAL (BATCH*SEQ)   // 4096

typedef __bf16 bf16;
typedef __bf16 bf16x8 __attribute__((ext_vector_type(8)));
typedef __bf16 bf16x4 __attribute__((ext_vector_type(4)));
typedef float  floatx4 __attribute__((ext_vector_type(4)));

// async global->LDS, 16B per lane. LDS dest is wave-uniform base + lane*16;
// conflicts handled by XOR-swizzle of 16B chunks applied to the GLOBAL source
// address (free).
__device__ __forceinline__ void gl2lds16(const bf16* g, bf16* l) {
    __builtin_amdgcn_global_load_lds(
        (const __attribute__((address_space(1))) unsigned int*)g,
        (__attribute__((address_space(3))) unsigned int*)l, 16, 0, 0);
}

// ---------------------------------------------------------------------------
// one combined fp32->bf16 conversion for q (1M float4), Wq (256K), Wo (256K)
// ---------------------------------------------------------------------------
__global__ void cvt_all(const float* __restrict__ q, const float* __restrict__ Wq,
                        const float* __restrict__ Wo, bf16* __restrict__ qb,
                        bf16* __restrict__ wqb, bf16* __restrict__ wob) {
    int i = blockIdx.x * 256 + threadIdx.x;       // 0 .. 1572863
    const float* src; bf16* dst; int off;
    if (i < 1048576)      { src = q;  dst = qb;  off = i; }
    else if (i < 1310720) { src = Wq; dst = wqb; off = i - 1048576; }
    else                  { src = Wo; dst = wob; off = i - 1310720; }
    float4 v = ((const float4*)src)[off];
    bf16x4 o;
    o[0] = (bf16)v.x; o[1] = (bf16)v.y; o[2] = (bf16)v.z; o[3] = (bf16)v.w;
    ((bf16x4*)dst)[off] = o;
}

// ---------------------------------------------------------------------------
// GEMM C = A * B^T + bias. 128(M)x64(N) tile, BK=32, 256 threads / 4 waves,
// 1-D grid 512, XCD-PINNED swizzle: xcd=lin&7 owns m-strips [xcd*4 ..xcd*4+3],
// so per XCD the working set is A-strips 4x256KB + whole B (2MB) = 3MB < 4MB L2.
// Round-7 measured the un-pinned version at ~45us (= L3-BW-bound at ~4.2TB/s
// over ~190MB of cross-XCD re-reads); pinning converts that traffic to L2.
// Double-buffered LDS via global_load_lds(16); tiles unpadded [row][32]
// (64B rows, 4x16B chunks), chunk swizzle c = sp ^ ((row>>1)&3) -> even banks.
// Wave w: wm=(w>>1)*64, wn=(w&1)*32; 4x2 grid of 16x16x32 MFMA.
// Frag layouts (HW-verified): A m=lane&15,k=quad*8+j; C/D col=lane&15,row=quad*4+r.
// MODE 0: fp32 out row-major + bias.
// MODE 1: bf16 out to projbf [B,H,S,Dh] + projT [B,H,Dh,S] via in-LDS transpose
//         (n-extent 64 = exactly one head per block column).
// ---------------------------------------------------------------------------
template<int MODE>
__global__ __launch_bounds__(256)
void gemm_bt_bias_t(const bf16* __restrict__ A, const bf16* __restrict__ B,
                    const float* __restrict__ bias, void* __restrict__ Cout,
                    bf16* __restrict__ Cout2, int M, int N, int K)
{
    __shared__ __align__(16) bf16 smem[12288];   // As[2][4096] | Bs[2][2048] = 24KB
    bf16* As = smem;            // [2][128*32]
    bf16* Bs = smem + 8192;     // [2][64*32]

    const int tid  = threadIdx.x;
    const int lane = tid & 63;
    const int wave = tid >> 6;             // 0..3
    const int quad = lane >> 4;
    const int l16  = lane & 15;
    const int lin  = blockIdx.x;           // 0..511
    const int m0   = ((lin & 7) * 4 + ((lin >> 3) & 3)) * 128;  // XCD-pinned m-strip
    const int n0   = (lin >> 5) * 64;
    const int wm   = (wave >> 1) * 64;
    const int wn   = (wave & 1) * 32;

    floatx4 acc[4][2];
#pragma unroll
    for (int i = 0; i < 4; i++)
#pragma unroll
        for (int j = 0; j < 2; j++) acc[i][j] = (floatx4){0.f, 0.f, 0.f, 0.f};

    // staging: A 8KB (2 issues/thread), B 4KB (1 issue/thread)
    const int srow = tid >> 2;                        // 0..63
    const int sp   = tid & 3;
    auto issue = [&](int buf, int k0) {
#pragma unroll
        for (int it = 0; it < 2; it++) {
            int row = it * 64 + srow;
            int c   = sp ^ ((row >> 1) & 3);
            gl2lds16(A + (size_t)(m0 + row) * K + k0 + c * 8,
                     &As[buf * 4096 + it * 2048 + tid * 8]);
        }
        {
            int c = sp ^ ((srow >> 1) & 3);
            gl2lds16(B + (size_t)(n0 + srow) * K + k0 + c * 8,
                     &Bs[buf * 2048 + tid * 8]);
        }
    };
    issue(0, 0);
    int buf = 0;
    for (int k0 = 0; k0 < K; k0 += 32, buf ^= 1) {
        __syncthreads();               // drains DMA of tile k0; WAR for buf^1
        if (k0 + 32 < K) issue(buf ^ 1, k0 + 32);
        bf16x8 af[4], bfr[2];
#pragma unroll
        for (int i = 0; i < 4; i++) {
            int row = wm + i * 16 + l16;
            af[i] = *(const bf16x8*)&As[buf * 4096 + row * 32 + ((quad ^ ((row >> 1) & 3)) * 8)];
        }
#pragma unroll
        for (int j = 0; j < 2; j++) {
            int row = wn + j * 16 + l16;
            bfr[j] = *(const bf16x8*)&Bs[buf * 2048 + row * 32 + ((quad ^ ((row >> 1) & 3)) * 8)];
        }
#pragma unroll
        for (int i = 0; i < 4; i++)
#pragma unroll
            for (int j = 0; j < 2; j++)
                acc[i][j] = __builtin_amdgcn_mfma_f32_16x16x32_bf16(
                    af[i], bfr[j], acc[i][j], 0, 0, 0);
    }

    if constexpr (MODE == 0) {
        float* C = (float*)Cout;
#pragma unroll
        for (int j = 0; j < 2; j++) {
            int col  = n0 + wn + j * 16 + l16;
            float bv = bias[col];
#pragma unroll
            for (int i = 0; i < 4; i++) {
                int rbase = m0 + wm + i * 16 + quad * 4;
#pragma unroll
                for (int r = 0; r < 4; r++)
                    C[(size_t)(rbase + r) * N + col] = acc[i][j][r] + bv;
            }
        }
    } else {
        bf16* Cb = (bf16*)Cout;
        const int h  = n0 >> 6;          // tile spans exactly one head
        const int b  = m0 >> 11;         // tile never crosses batch boundary
        bf16x4 tile[4][2];
#pragma unroll
        for (int j = 0; j < 2; j++) {
            int dL   = wn + j * 16 + l16;            // 0..63
            float bv = bias[n0 + dL];
#pragma unroll
            for (int i = 0; i < 4; i++) {
                int sl = wm + i * 16 + quad * 4;     // local s, 0..127
                int s0 = (m0 & 2047) + sl;
#pragma unroll
                for (int r = 0; r < 4; r++) {
                    float v = acc[i][j][r] + bv;
                    tile[i][j][r] = (bf16)v;
                    Cb[(((size_t)(b * N_HEADS + h) * SEQ + (s0 + r)) << 6) + dL] = (bf16)v;
                }
            }
        }
        // in-LDS transpose: T[dL=64][sL=128] (16KB, reuse smem),
        // 16B-chunk swizzle phys = (sl>>3) ^ (dL&15)
        __syncthreads();
#pragma unroll
        for (int j = 0; j < 2; j++) {
            int dL = wn + j * 16 + l16;
#pragma unroll
            for (int i = 0; i < 4; i++) {
                int sl = wm + i * 16 + quad * 4;
                *(bf16x4*)&smem[dL * 128 + (((sl >> 3) ^ (dL & 15)) * 8) + (sl & 7)] =
                    tile[i][j];
            }
        }
        __syncthreads();
        // coalesced projT stores: thread -> (dL = tid>>2, 4 chunks of 16B)
        {
            int dL    = tid >> 2;
            int sbase = m0 & 2047;
            bf16* dstrow = Cout2 + ((size_t)(b * N_HEADS + h) * 64 + dL) * SEQ + sbase;
#pragma unroll
            for (int cc = 0; cc < 4; cc++) {
                int c    = (tid & 3) * 4 + cc;
                int phys = c ^ (dL & 15);
                *(bf16x8*)(dstrow + c * 8) = *(const bf16x8*)&smem[dL * 128 + phys * 8];
            }
        }
    }
}

// ---------------------------------------------------------------------------
// MFMA flash attention. 256-thread / 4-wave blocks (2 waves/SIMD), 32 q/wave,
// 128-q tile, K-tiles of 128 keys, double-buffered K/V DMA prefetch.
// 1-D grid 512 with XCD-pinned mapping: bh=(lin&7)*4+(lin>>7) (FETCH 68->8MB).
// Ks [128 keys][64 d] unpadded, chunk swizzle c^(row&7)  -> even banks.
// Vt [64 d][128 keys] unpadded, chunk swizzle c^(row&15) -> even banks.
// Pt [128 q][40]: per-wave-private rows; written from S^T C-layout as b64.
// S^T: A=K,B=Q -> D[key][q]; PV: A=Vt,B=Pt -> O^T[d][q]; fixed exp(s/8-16)
// via __expf (round-7 exp2f lowered to the slow __ocml path: VALUBusy +11pts).
// (scores provably <= ~12, no max pass; validated absmax 0.023).
// ---------------------------------------------------------------------------
__global__ __launch_bounds__(256)
void flash_attn(const bf16* __restrict__ projbf, const bf16* __restrict__ projT,
                bf16* __restrict__ vals)
{
    __shared__ __align__(16) bf16 Ks[2][128 * 64];   // 2 x 16 KB
    __shared__ __align__(16) bf16 Vt[2][64 * 128];   // 2 x 16 KB
    __shared__ __align__(16) bf16 Pt[128 * 40];      // 10 KB

    const int tid  = threadIdx.x;
    const int lane = tid & 63;
    const int wave = tid >> 6;          // 0..3
    const int quad = lane >> 4;
    const int l16  = lane & 15;
    const int lin  = blockIdx.x;
    const int bh   = (lin & 7) * 4 + (lin >> 7);     // XCD-pinned head
    const int q0   = ((lin >> 3) & 15) * 128;
    const bf16* hK  = projbf + (size_t)bh * SEQ * 64;
    const bf16* hVt = projT  + (size_t)bh * 64 * SEQ;
    const int wq0  = wave * 32;

    // persistent Q B-frags: qf[nb][ks], n=q (16 per nb), k=d
    bf16x8 qf[2][2];
#pragma unroll
    for (int nb = 0; nb < 2; nb++)
#pragma unroll
        for (int ks = 0; ks < 2; ks++)
            qf[nb][ks] = *(const bf16x8*)(hK + (size_t)(q0 + wq0 + nb * 16 + l16) * 64
                                          + ks * 32 + quad * 8);

    floatx4 oacc[4][2];                 // [mb=d-block][nb=q-block]
#pragma unroll
    for (int mb = 0; mb < 4; mb++)
#pragma unroll
        for (int nb = 0; nb < 2; nb++) oacc[mb][nb] = (floatx4){0.f, 0.f, 0.f, 0.f};
    float lsum[2] = {0.f, 0.f};

    // DMA one K+V tile pair (32 KB): 4 issues each, 256 threads x 16B
    auto issue = [&](int buf, int k0) {
#pragma unroll
        for (int it = 0; it < 4; it++) {            // K: 32 rows per issue
            int row = it * 32 + (tid >> 3);
            int c   = (tid & 7) ^ (row & 7);
            gl2lds16(hK + (size_t)(k0 + row) * 64 + c * 8,
                     &Ks[buf][it * 2048 + tid * 8]);
        }
#pragma unroll
        for (int it = 0; it < 4; it++) {            // V^T: 16 d-rows per issue
            int row = it * 16 + (tid >> 4);
            int c   = (tid & 15) ^ (row & 15);
            gl2lds16(hVt + (size_t)row * SEQ + k0 + c * 8,
                     &Vt[buf][it * 2048 + tid * 8]);
        }
    };
    issue(0, 0);
    int buf = 0;
    for (int k0 = 0; k0 < SEQ; k0 += 128, buf ^= 1) {
        __syncthreads();                // drains DMA of tile k0 (prefetched); WAR buf^1
        if (k0 + 128 < SEQ) issue(buf ^ 1, k0 + 128);

#pragma unroll
        for (int ck = 0; ck < 4; ck++) {            // 32-key chunks
            // ---- S^T phase ----
#pragma unroll
            for (int kb = 0; kb < 2; kb++) {
                int krow = ck * 32 + kb * 16 + l16;
                bf16x8 kf0 = *(const bf16x8*)&Ks[buf][krow * 64 + ((quad ^ (krow & 7)) * 8)];
                bf16x8 kf1 = *(const bf16x8*)&Ks[buf][krow * 64 + (((4 + quad) ^ (krow & 7)) * 8)];
                floatx4 sacc[2];
#pragma unroll
                for (int nb = 0; nb < 2; nb++) {
                    sacc[nb] = __builtin_amdgcn_mfma_f32_16x16x32_bf16(
                        kf0, qf[nb][0], (floatx4){0.f, 0.f, 0.f, 0.f}, 0, 0, 0);
                    sacc[nb] = __builtin_amdgcn_mfma_f32_16x16x32_bf16(
                        kf1, qf[nb][1], sacc[nb], 0, 0, 0);
                }
#pragma unroll
                for (int nb = 0; nb < 2; nb++) {
                    bf16x4 p4; float ps = 0.f;
#pragma unroll
                    for (int r = 0; r < 4; r++) {
                        float p = __expf(sacc[nb][r] * 0.125f - 16.0f);
                        p4[r] = (bf16)p; ps += p;
                    }
                    lsum[nb] += ps;
                    *(bf16x4*)&Pt[(wq0 + nb * 16 + l16) * 40 + kb * 16 + quad * 4] = p4;
                }
            }
            // ---- PV phase over these 32 keys (Pt rows wave-private) ----
            bf16x8 pf[2];
#pragma unroll
            for (int nb = 0; nb < 2; nb++)
                pf[nb] = *(const bf16x8*)&Pt[(wq0 + nb * 16 + l16) * 40 + quad * 8];
#pragma unroll
            for (int mb = 0; mb < 4; mb++) {
                int vrow = mb * 16 + l16;
                bf16x8 vf = *(const bf16x8*)&Vt[buf][vrow * 128
                                                + (((ck * 4 + quad) ^ (vrow & 15)) * 8)];
#pragma unroll
                for (int nb = 0; nb < 2; nb++)
                    oacc[mb][nb] = __builtin_amdgcn_mfma_f32_16x16x32_bf16(
                        vf, pf[nb], oacc[mb][nb], 0, 0, 0);
            }
        }
    }

    // row sums: reduce across quads (each quad summed a disjoint key subset)
#pragma unroll
    for (int nb = 0; nb < 2; nb++) {
        lsum[nb] += __shfl_xor(lsum[nb], 16);
        lsum[nb] += __shfl_xor(lsum[nb], 32);
    }
    const int b = bh >> 4, h = bh & 15;
#pragma unroll
    for (int nb = 0; nb < 2; nb++) {
        float rinv = 1.0f / lsum[nb];
        int q = q0 + wq0 + nb * 16 + l16;
#pragma unroll
        for (int mb = 0; mb < 4; mb++) {
            bf16x4 o4;
#pragma unroll
            for (int r = 0; r < 4; r++) o4[r] = (bf16)(oacc[mb][nb][r] * rinv);
            *(bf16x4*)&vals[((size_t)b * SEQ + q) * D_MODEL + h * 64 + mb * 16 + quad * 4] = o4;
        }
    }
}

// ---------------------------------------------------------------------------
extern "C" void kernel_launch(void* const* d_in, const int* in_sizes, int n_in,
                              void* d_out, int out_size, void* d_ws, size_t ws_size,
                              hipStream_t stream)
{
    const float* q  = (const float*)d_in[0];
    const float* Wq = (const float*)d_in[1];
    const float* bq = (const float*)d_in[2];
    const float* Wo = (const float*)d_in[3];
    const float* bo = (const float*)d_in[4];
    float* out = (float*)d_out;

    char* ws = (char*)d_ws;
    bf16* qbf    = (bf16*)(ws);                        // 8 MB
    bf16* Wqbf   = (bf16*)(ws + (size_t)( 8 << 20));   // 2 MB
    bf16* Wobf   = (bf16*)(ws + (size_t)(10 << 20));   // 2 MB
    bf16* projbf = (bf16*)(ws + (size_t)(12 << 20));   // 8 MB  [B,H,S,Dh]
    bf16* projT  = (bf16*)(ws + (size_t)(20 << 20));   // 8 MB  [B,H,Dh,S]
    bf16* valsb  = (bf16*)(ws + (size_t)(28 << 20));   // 8 MB  [B,S,D]

    cvt_all<<<6144, 256, 0, stream>>>(q, Wq, Wo, qbf, Wqbf, Wobf);

    // proj = q @ Wq^T + bq -> projbf [B,H,S,Dh] + projT [B,H,Dh,S]
    gemm_bt_bias_t<1><<<512, 256, 0, stream>>>(qbf, Wqbf, bq, (void*)projbf,
                                               projT, M_TOTAL, D_MODEL, D_MODEL);

    flash_attn<<<512, 256, 0, stream>>>(projbf, projT, valsb);

    gemm_bt_bias_t<0><<<512, 256, 0, stream>>>(valsb, Wobf, bo, (void*)out,
                                               nullptr, M_TOTAL, D_MODEL, D_MODEL);
}

// Round 9
// 160.888 us; speedup vs baseline: 1.1280x; 1.0362x over previous
//
#include <hip/hip_runtime.h>

#define D_MODEL 1024
#define N_HEADS 16
#define HEAD_DIM 64
#define SEQ 2048
#define BATCH 2
#define M_TOTAL (BATCH*SEQ)   // 4096

typedef __bf16 bf16;
typedef __bf16 bf16x8 __attribute__((ext_vector_type(8)));
typedef __bf16 bf16x4 __attribute__((ext_vector_type(4)));
typedef float  floatx4 __attribute__((ext_vector_type(4)));

#if __has_builtin(__builtin_amdgcn_exp2f)
#define EXP2F(x) __builtin_amdgcn_exp2f(x)
#else
#define EXP2F(x) __expf(0.69314718f * (x))
#endif

// async global->LDS, 16B per lane. LDS dest is wave-uniform base + lane*16;
// conflicts handled by XOR-swizzle of 16B chunks applied to the GLOBAL source
// address (free).
__device__ __forceinline__ void gl2lds16(const bf16* g, bf16* l) {
    __builtin_amdgcn_global_load_lds(
        (const __attribute__((address_space(1))) unsigned int*)g,
        (__attribute__((address_space(3))) unsigned int*)l, 16, 0, 0);
}

// ---------------------------------------------------------------------------
// one combined fp32->bf16 conversion for q (1M float4), Wq (256K), Wo (256K)
// ---------------------------------------------------------------------------
__global__ void cvt_all(const float* __restrict__ q, const float* __restrict__ Wq,
                        const float* __restrict__ Wo, bf16* __restrict__ qb,
                        bf16* __restrict__ wqb, bf16* __restrict__ wob) {
    int i = blockIdx.x * 256 + threadIdx.x;       // 0 .. 1572863
    const float* src; bf16* dst; int off;
    if (i < 1048576)      { src = q;  dst = qb;  off = i; }
    else if (i < 1310720) { src = Wq; dst = wqb; off = i - 1048576; }
    else                  { src = Wo; dst = wob; off = i - 1310720; }
    float4 v = ((const float4*)src)[off];
    bf16x4 o;
    o[0] = (bf16)v.x; o[1] = (bf16)v.y; o[2] = (bf16)v.z; o[3] = (bf16)v.w;
    ((bf16x4*)dst)[off] = o;
}

// ---------------------------------------------------------------------------
// GEMM C = A * B^T + bias. 128(M)x64(N) tile, BK=64 (16 iterations: rounds 6-8
// showed neutrality to everything EXCEPT barrier count -> halve the barriers,
// double MFMA/barrier to 16/wave). 256 threads / 4 waves, 48KB LDS -> 2
// blocks/CU. 1-D grid 512, XCD-pinned: xcd=lin&7 owns m-strips 4x..4x+3
// (A 1MB + B 2MB per XCD < 4MB L2).
// Tiles unpadded [row][64] (128B rows, 8x16B chunks), chunk swizzle
// phys = logical ^ (row&7) -> frag reads 2-way (free, m136).
// Frag layouts (HW-verified): A m=lane&15,k=quad*8+j; C/D col=lane&15,row=quad*4+r.
// MODE 0: fp32 out row-major + bias.
// MODE 1: bf16 out to projbf [B,H,S,Dh] + projT [B,H,Dh,S] via in-LDS transpose.
// ---------------------------------------------------------------------------
template<int MODE>
__global__ __launch_bounds__(256)
void gemm_bt_bias_t(const bf16* __restrict__ A, const bf16* __restrict__ B,
                    const float* __restrict__ bias, void* __restrict__ Cout,
                    bf16* __restrict__ Cout2, int M, int N, int K)
{
    __shared__ __align__(16) bf16 smem[24576];   // As[2][8192] | Bs[2][4096] = 48KB
    bf16* As = smem;             // [2][128*64]
    bf16* Bs = smem + 16384;     // [2][64*64]

    const int tid  = threadIdx.x;
    const int lane = tid & 63;
    const int wave = tid >> 6;             // 0..3
    const int quad = lane >> 4;
    const int l16  = lane & 15;
    const int lin  = blockIdx.x;           // 0..511
    const int m0   = ((lin & 7) * 4 + ((lin >> 3) & 3)) * 128;  // XCD-pinned m-strip
    const int n0   = (lin >> 5) * 64;
    const int wm   = (wave >> 1) * 64;
    const int wn   = (wave & 1) * 32;

    floatx4 acc[4][2];
#pragma unroll
    for (int i = 0; i < 4; i++)
#pragma unroll
        for (int j = 0; j < 2; j++) acc[i][j] = (floatx4){0.f, 0.f, 0.f, 0.f};

    // staging one 24KB tile pair: A 16KB (4 issues/thread), B 8KB (2 issues)
    auto issue = [&](int buf, int k0) {
#pragma unroll
        for (int it = 0; it < 4; it++) {
            int s = it * 256 + tid;          // 0..1023 chunk slots
            int row = s >> 3, cl = (s & 7) ^ (row & 7);
            gl2lds16(A + (size_t)(m0 + row) * K + k0 + cl * 8, &As[buf * 8192 + s * 8]);
        }
#pragma unroll
        for (int it = 0; it < 2; it++) {
            int s = it * 256 + tid;          // 0..511
            int row = s >> 3, cl = (s & 7) ^ (row & 7);
            gl2lds16(B + (size_t)(n0 + row) * K + k0 + cl * 8, &Bs[buf * 4096 + s * 8]);
        }
    };
    issue(0, 0);
    int buf = 0;
    for (int k0 = 0; k0 < K; k0 += 64, buf ^= 1) {
        __syncthreads();               // drains DMA of tile k0; WAR for buf^1
        if (k0 + 64 < K) issue(buf ^ 1, k0 + 64);
#pragma unroll
        for (int ks = 0; ks < 2; ks++) {
            bf16x8 af[4], bfr[2];
#pragma unroll
            for (int i = 0; i < 4; i++) {
                int row = wm + i * 16 + l16;
                int phys = (ks * 4 + quad) ^ (row & 7);
                af[i] = *(const bf16x8*)&As[buf * 8192 + row * 64 + phys * 8];
            }
#pragma unroll
            for (int j = 0; j < 2; j++) {
                int row = wn + j * 16 + l16;
                int phys = (ks * 4 + quad) ^ (row & 7);
                bfr[j] = *(const bf16x8*)&Bs[buf * 4096 + row * 64 + phys * 8];
            }
#pragma unroll
            for (int i = 0; i < 4; i++)
#pragma unroll
                for (int j = 0; j < 2; j++)
                    acc[i][j] = __builtin_amdgcn_mfma_f32_16x16x32_bf16(
                        af[i], bfr[j], acc[i][j], 0, 0, 0);
        }
    }

    if constexpr (MODE == 0) {
        float* C = (float*)Cout;
#pragma unroll
        for (int j = 0; j < 2; j++) {
            int col  = n0 + wn + j * 16 + l16;
            float bv = bias[col];
#pragma unroll
            for (int i = 0; i < 4; i++) {
                int rbase = m0 + wm + i * 16 + quad * 4;
#pragma unroll
                for (int r = 0; r < 4; r++)
                    C[(size_t)(rbase + r) * N + col] = acc[i][j][r] + bv;
            }
        }
    } else {
        bf16* Cb = (bf16*)Cout;
        const int h  = n0 >> 6;          // tile spans exactly one head
        const int b  = m0 >> 11;         // tile never crosses batch boundary
        bf16x4 tile[4][2];
#pragma unroll
        for (int j = 0; j < 2; j++) {
            int dL   = wn + j * 16 + l16;            // 0..63
            float bv = bias[n0 + dL];
#pragma unroll
            for (int i = 0; i < 4; i++) {
                int sl = wm + i * 16 + quad * 4;     // local s, 0..127
                int s0 = (m0 & 2047) + sl;
#pragma unroll
                for (int r = 0; r < 4; r++) {
                    float v = acc[i][j][r] + bv;
                    tile[i][j][r] = (bf16)v;
                    Cb[(((size_t)(b * N_HEADS + h) * SEQ + (s0 + r)) << 6) + dL] = (bf16)v;
                }
            }
        }
        // in-LDS transpose: T[dL=64][sL=128] (16KB, reuse smem),
        // 16B-chunk swizzle phys = (sl>>3) ^ (dL&15)
        __syncthreads();
#pragma unroll
        for (int j = 0; j < 2; j++) {
            int dL = wn + j * 16 + l16;
#pragma unroll
            for (int i = 0; i < 4; i++) {
                int sl = wm + i * 16 + quad * 4;
                *(bf16x4*)&smem[dL * 128 + (((sl >> 3) ^ (dL & 15)) * 8) + (sl & 7)] =
                    tile[i][j];
            }
        }
        __syncthreads();
        // coalesced projT stores: thread -> (dL = tid>>2, 4 chunks of 16B)
        {
            int dL    = tid >> 2;
            int sbase = m0 & 2047;
            bf16* dstrow = Cout2 + ((size_t)(b * N_HEADS + h) * 64 + dL) * SEQ + sbase;
#pragma unroll
            for (int cc = 0; cc < 4; cc++) {
                int c    = (tid & 3) * 4 + cc;
                int phys = c ^ (dL & 15);
                *(bf16x8*)(dstrow + c * 8) = *(const bf16x8*)&smem[dL * 128 + phys * 8];
            }
        }
    }
}

// ---------------------------------------------------------------------------
// MFMA flash attention. 256-thread / 4-wave blocks, 32 q/wave, 128-q tile.
// K-tiles of 64 keys, double-buffered DMA prefetch; LDS 43KB -> 3 blocks/CU
// (12 waves/CU: cross-block overlap hides the per-tile barrier drain).
// 1-D grid 512, XCD-pinned: bh=(lin&7)*4+(lin>>7) (FETCH 68->8MB, round 6).
// Ks [64 keys][64 d] unpadded 128B rows, chunk swizzle phys=c^(row&7) (2-way).
// Vt [64 d][64 keys] unpadded 128B rows, same swizzle.
// Pt [128 q][40]: per-wave-private rows; written from S^T C-layout as b64.
// S^T: A=K,B=Q -> D[key][q]; PV: A=Vt,B=Pt -> O^T[d][q].
// Softmax: fixed stabilizer exp(s/8-16) as single v_fma+v_exp via
// __builtin_amdgcn_exp2f (libm exp2f is the slow checked path - round 7).
// Scores provably <= ~12 -> no max pass; validated absmax 0.023.
// ---------------------------------------------------------------------------
__global__ __launch_bounds__(256)
void flash_attn(const bf16* __restrict__ projbf, const bf16* __restrict__ projT,
                bf16* __restrict__ vals)
{
    __shared__ __align__(16) bf16 Ks[2][64 * 64];   // 2 x 8 KB
    __shared__ __align__(16) bf16 Vt[2][64 * 64];   // 2 x 8 KB
    __shared__ __align__(16) bf16 Pt[128 * 40];     // 10 KB

    const int tid  = threadIdx.x;
    const int lane = tid & 63;
    const int wave = tid >> 6;          // 0..3
    const int quad = lane >> 4;
    const int l16  = lane & 15;
    const int lin  = blockIdx.x;
    const int bh   = (lin & 7) * 4 + (lin >> 7);     // XCD-pinned head
    const int q0   = ((lin >> 3) & 15) * 128;
    const bf16* hK  = projbf + (size_t)bh * SEQ * 64;
    const bf16* hVt = projT  + (size_t)bh * 64 * SEQ;
    const int wq0  = wave * 32;

    // persistent Q B-frags: qf[nb][ks], n=q (16 per nb), k=d
    bf16x8 qf[2][2];
#pragma unroll
    for (int nb = 0; nb < 2; nb++)
#pragma unroll
        for (int ks = 0; ks < 2; ks++)
            qf[nb][ks] = *(const bf16x8*)(hK + (size_t)(q0 + wq0 + nb * 16 + l16) * 64
                                          + ks * 32 + quad * 8);

    floatx4 oacc[4][2];                 // [mb=d-block][nb=q-block]
#pragma unroll
    for (int mb = 0; mb < 4; mb++)
#pragma unroll
        for (int nb = 0; nb < 2; nb++) oacc[mb][nb] = (floatx4){0.f, 0.f, 0.f, 0.f};
    float lsum[2] = {0.f, 0.f};

    // DMA one 64-key K+V tile pair (16 KB): 2+2 issues/thread
    auto issue = [&](int buf, int k0) {
#pragma unroll
        for (int it = 0; it < 2; it++) {
            int s = it * 256 + tid;          // 0..511 chunk slots
            int row = s >> 3, cl = (s & 7) ^ (row & 7);
            gl2lds16(hK + (size_t)(k0 + row) * 64 + cl * 8, &Ks[buf][s * 8]);
        }
#pragma unroll
        for (int it = 0; it < 2; it++) {
            int s = it * 256 + tid;
            int row = s >> 3, cl = (s & 7) ^ (row & 7);
            gl2lds16(hVt + (size_t)row * SEQ + k0 + cl * 8, &Vt[buf][s * 8]);
        }
    };
    issue(0, 0);
    int buf = 0;
    for (int k0 = 0; k0 < SEQ; k0 += 64, buf ^= 1) {
        __syncthreads();                // drains DMA of tile k0 (prefetched); WAR buf^1
        if (k0 + 64 < SEQ) issue(buf ^ 1, k0 + 64);

#pragma unroll
        for (int ck = 0; ck < 2; ck++) {            // 32-key chunks
            // ---- S^T phase ----
#pragma unroll
            for (int kb = 0; kb < 2; kb++) {
                int krow = ck * 32 + kb * 16 + l16;
                bf16x8 kf0 = *(const bf16x8*)&Ks[buf][krow * 64 + ((quad ^ (krow & 7)) * 8)];
                bf16x8 kf1 = *(const bf16x8*)&Ks[buf][krow * 64 + (((4 + quad) ^ (krow & 7)) * 8)];
                floatx4 sacc[2];
#pragma unroll
                for (int nb = 0; nb < 2; nb++) {
                    sacc[nb] = __builtin_amdgcn_mfma_f32_16x16x32_bf16(
                        kf0, qf[nb][0], (floatx4){0.f, 0.f, 0.f, 0.f}, 0, 0, 0);
                    sacc[nb] = __builtin_amdgcn_mfma_f32_16x16x32_bf16(
                        kf1, qf[nb][1], sacc[nb], 0, 0, 0);
                }
#pragma unroll
                for (int nb = 0; nb < 2; nb++) {
                    bf16x4 p4; float ps = 0.f;
#pragma unroll
                    for (int r = 0; r < 4; r++) {
                        // exp(s/8 - 16) = exp2(s*0.18033688 - 23.083120)
                        float p = EXP2F(fmaf(sacc[nb][r], 0.18033688f, -23.083120f));
                        p4[r] = (bf16)p; ps += p;
                    }
                    lsum[nb] += ps;
                    *(bf16x4*)&Pt[(wq0 + nb * 16 + l16) * 40 + kb * 16 + quad * 4] = p4;
                }
            }
            // ---- PV phase over these 32 keys (Pt rows wave-private) ----
            bf16x8 pf[2];
#pragma unroll
            for (int nb = 0; nb < 2; nb++)
                pf[nb] = *(const bf16x8*)&Pt[(wq0 + nb * 16 + l16) * 40 + quad * 8];
#pragma unroll
            for (int mb = 0; mb < 4; mb++) {
                int vrow = mb * 16 + l16;
                bf16x8 vf = *(const bf16x8*)&Vt[buf][vrow * 64
                                                + (((ck * 4 + quad) ^ (vrow & 7)) * 8)];
#pragma unroll
                for (int nb = 0; nb < 2; nb++)
                    oacc[mb][nb] = __builtin_amdgcn_mfma_f32_16x16x32_bf16(
                        vf, pf[nb], oacc[mb][nb], 0, 0, 0);
            }
        }
    }

    // row sums: reduce across quads (each quad summed a disjoint key subset)
#pragma unroll
    for (int nb = 0; nb < 2; nb++) {
        lsum[nb] += __shfl_xor(lsum[nb], 16);
        lsum[nb] += __shfl_xor(lsum[nb], 32);
    }
    const int b = bh >> 4, h = bh & 15;
#pragma unroll
    for (int nb = 0; nb < 2; nb++) {
        float rinv = 1.0f / lsum[nb];
        int q = q0 + wq0 + nb * 16 + l16;
#pragma unroll
        for (int mb = 0; mb < 4; mb++) {
            bf16x4 o4;
#pragma unroll
            for (int r = 0; r < 4; r++) o4[r] = (bf16)(oacc[mb][nb][r] * rinv);
            *(bf16x4*)&vals[((size_t)b * SEQ + q) * D_MODEL + h * 64 + mb * 16 + quad * 4] = o4;
        }
    }
}

// ---------------------------------------------------------------------------
extern "C" void kernel_launch(void* const* d_in, const int* in_sizes, int n_in,
                              void* d_out, int out_size, void* d_ws, size_t ws_size,
                              hipStream_t stream)
{
    const float* q  = (const float*)d_in[0];
    const float* Wq = (const float*)d_in[1];
    const float* bq = (const float*)d_in[2];
    const float* Wo = (const float*)d_in[3];
    const float* bo = (const float*)d_in[4];
    float* out = (float*)d_out;

    char* ws = (char*)d_ws;
    bf16* qbf    = (bf16*)(ws);                        // 8 MB
    bf16* Wqbf   = (bf16*)(ws + (size_t)( 8 << 20));   // 2 MB
    bf16* Wobf   = (bf16*)(ws + (size_t)(10 << 20));   // 2 MB
    bf16* projbf = (bf16*)(ws + (size_t)(12 << 20));   // 8 MB  [B,H,S,Dh]
    bf16* projT  = (bf16*)(ws + (size_t)(20 << 20));   // 8 MB  [B,H,Dh,S]
    bf16* valsb  = (bf16*)(ws + (size_t)(28 << 20));   // 8 MB  [B,S,D]

    cvt_all<<<6144, 256, 0, stream>>>(q, Wq, Wo, qbf, Wqbf, Wobf);

    // proj = q @ Wq^T + bq -> projbf [B,H,S,Dh] + projT [B,H,Dh,S]
    gemm_bt_bias_t<1><<<512, 256, 0, stream>>>(qbf, Wqbf, bq, (void*)projbf,
                                               projT, M_TOTAL, D_MODEL, D_MODEL);

    flash_attn<<<512, 256, 0, stream>>>(projbf, projT, valsb);

    gemm_bt_bias_t<0><<<512, 256, 0, stream>>>(valsb, Wobf, bo, (void*)out,
                                               nullptr, M_TOTAL, D_MODEL, D_MODEL);
}